// Round 7
// baseline (92.836 us; speedup 1.0000x reference)
//
#include <hip/hip_runtime.h>
#include <hip/hip_bf16.h>
#include <math.h>

typedef float  float4v __attribute__((ext_vector_type(4)));
typedef float  f32x16  __attribute__((ext_vector_type(16)));
typedef _Float16 half8  __attribute__((ext_vector_type(8)));
typedef _Float16 h2v    __attribute__((ext_vector_type(2)));
typedef __fp16  fp16x2 __attribute__((ext_vector_type(2)));
typedef unsigned int   uN4 __attribute__((ext_vector_type(4)));
typedef unsigned int   uint2v __attribute__((ext_vector_type(2)));
typedef unsigned short us4 __attribute__((ext_vector_type(4)));

constexpr int Cc = 256;    // C_IN
constexpr int Ci = 128;    // C_INT
constexpr int Nn = 4096;   // H*W
constexpr float LOG2E = 1.4426950408889634f;

// ws layout (ushort units). All fp16 unless noted.
constexpr size_t KT  = 0;          // K [b][n][o]   (4 MB)  — log2e-scaled
constexpr size_t VT  = 2097152;    // V [b][m][o]   (4 MB)
constexpr size_t QT  = 4194304;    // Q [b][o][n]   (4 MB)
constexpr size_t OB  = 6291456;    // O partials [mh][b][n][o], 4 x 4 MB
constexpr size_t OSZ = 2097152;
constexpr size_t XH  = 6291456;    // x^T [b][n][c] fp16 (8 MB) — ALIASES OB[0..1]
constexpr size_t STAT_BYTE = 29360128;  // Mst[16][4096], Lst[16][4096] f32
constexpr size_t WH  = 14942208;   // stacked weights fp16 [384][256]
constexpr size_t WOH = 15040512;   // w_w fp16 [256][128]

__device__ __forceinline__ f32x16 zero16() {
  f32x16 z;
  #pragma unroll
  for (int r = 0; r < 16; ++r) z[r] = 0.0f;
  return z;
}
__device__ __forceinline__ unsigned pkf(float x, float y) {
  union { fp16x2 h; unsigned u; } c;
  c.h = __builtin_amdgcn_cvt_pkrtz(x, y);
  return c.u;
}
__device__ __forceinline__ f32x16 mfmaf16(half8 a, half8 b, f32x16 c) {
  return __builtin_amdgcn_mfma_f32_32x32x16_f16(a, b, c, 0, 0, 0);
}
__device__ __forceinline__ float h2f(unsigned short u) {
  union { unsigned short u; _Float16 h; } c; c.u = u; return (float)c.h;
}
__device__ __forceinline__ unsigned short f2h(float x) {
  union { _Float16 h; unsigned short u; } c; c.h = (_Float16)x; return c.u;
}
__device__ __forceinline__ unsigned pkfma(unsigned a, unsigned b, unsigned c) {
  union { unsigned u; h2v h; } A, B, C, R;
  A.u = a; B.u = b; C.u = c;
  R.h = A.h * B.h + C.h;
  return R.u;
}
__device__ __forceinline__ unsigned pkmul(unsigned a, unsigned b) {
  union { unsigned u; h2v h; } A, B, R;
  A.u = a; B.u = b;
  R.h = A.h * B.h;
  return R.u;
}
// native 2^x (logits are pre-scaled to log2 domain).
__device__ __forceinline__ float ex2(float x) {
  float r;
  asm volatile("v_exp_f32 %0, %1\n\ts_nop 0" : "=v"(r) : "v"(x));
  return r;
}
// async global->LDS, 16B per lane. dest must be wave-uniform base + lane*16.
__device__ __forceinline__ void gload16(const unsigned short* src, unsigned char* lds) {
  __builtin_amdgcn_global_load_lds(
      (const __attribute__((address_space(1))) unsigned int*)src,
      (__attribute__((address_space(3))) unsigned int*)lds,
      16, 0, 0);
}

// PV A-fragment from this lane's 8 P-values via permlane32_swap (T12).
__device__ __forceinline__ half8 pfrag2(float p0, float p1, float p2, float p3,
                                        float p4, float p5, float p6, float p7) {
  unsigned a0 = pkf(p0, p1), a1 = pkf(p2, p3);
  unsigned b0 = pkf(p4, p5), b1 = pkf(p6, p7);
  uint2v rA = __builtin_amdgcn_permlane32_swap(a0, b0, false, false);
  uint2v rB = __builtin_amdgcn_permlane32_swap(a1, b1, false, false);
  union { unsigned u[4]; half8 h; } r;
  r.u[0] = rA.x; r.u[1] = rB.x; r.u[2] = rA.y; r.u[3] = rB.y;
  return r.h;
}

// ---------------------------------------------------------------------------
// Kernel 0: prep — x transpose to fp16 + weight conversion (unchanged).
// ---------------------------------------------------------------------------
__global__ __launch_bounds__(256)
void prep_kernel(const float* __restrict__ x,
                 const float* __restrict__ tw, const float* __restrict__ pw,
                 const float* __restrict__ gw, const float* __restrict__ ww,
                 unsigned short* __restrict__ ws16) {
  const int L = blockIdx.x;            // 1024 = b(4) x nt(64) x ct(4)
  const int b = L >> 8, rem = L & 255, nt = rem >> 2, ct = rem & 3;
  const int n0 = nt * 64, c0 = ct * 64;
  __shared__ unsigned short T[64][68];
  const int tid = threadIdx.x;
  const int tn = (tid & 15) * 4, tc = tid >> 4;

  #pragma unroll
  for (int it = 0; it < 4; ++it) {
    const int c = it*16 + tc;
    float4v v = *(const float4v*)(x + (((size_t)(b*256 + c0 + c)) << 12) + n0 + tn);
    #pragma unroll
    for (int k = 0; k < 4; ++k) T[tn + k][c] = f2h(v[k]);
  }

  if (L < 128) {    // weight conversion fold
    int i = L*1024 + tid*4;
    const float* src; unsigned short* dst; float sc = 1.0f;
    if (i < 32768)      { src = tw + i;           dst = ws16 + WH + i; sc = LOG2E; }
    else if (i < 65536) { src = pw + (i - 32768); dst = ws16 + WH + i; }
    else if (i < 98304) { src = gw + (i - 65536); dst = ws16 + WH + i; }
    else                { src = ww + (i - 98304); dst = ws16 + WOH + (i - 98304); }
    float4v v = *(const float4v*)src;
    us4 o;
    #pragma unroll
    for (int k = 0; k < 4; ++k) o[k] = f2h(v[k] * sc);
    *(us4*)dst = o;
  }
  __syncthreads();

  const int wn = tid >> 4, wc = (tid & 15) * 4;
  #pragma unroll
  for (int it = 0; it < 4; ++it) {
    const int n = it*16 + wn;
    us4 o;
    #pragma unroll
    for (int k = 0; k < 4; ++k) o[k] = T[n][wc + k];
    *(us4*)(ws16 + XH + (((size_t)(b*4096 + n0 + n)) << 8) + c0 + wc) = o;
  }
}

// ---------------------------------------------------------------------------
// Kernel 1: projections via MFMA, no LDS (unchanged).
// ---------------------------------------------------------------------------
__global__ __launch_bounds__(256)
void proj_kernel(const float* __restrict__ tb, const float* __restrict__ pb,
                 const float* __restrict__ gb, unsigned short* __restrict__ ws16) {
  const int L = blockIdx.x;          // 384
  const int p = L >> 7;              // 0=K,1=V,2=Q
  const int rem = L & 127;
  const int b = rem & 3, nt = rem >> 2;
  const int n0 = nt * 128;
  const int tid = threadIdx.x, w = tid >> 6, lane = tid & 63;
  const int l31 = lane & 31, g = lane >> 5;

  const unsigned short* xrow =
      ws16 + XH + (((size_t)(b*4096 + n0 + w*32 + l31)) << 8) + g*8;
  const unsigned short* wbase = ws16 + WH + (size_t)p*32768 + g*8;

  f32x16 acc[4];
  #pragma unroll
  for (int ot = 0; ot < 4; ++ot) acc[ot] = zero16();

  if (p < 2) {
    #pragma unroll
    for (int kt = 0; kt < 16; ++kt) {
      half8 xf = *(const half8*)(xrow + kt*16);
      #pragma unroll
      for (int ot = 0; ot < 4; ++ot) {
        half8 wf = *(const half8*)(wbase + (((size_t)(ot*32 + l31)) << 8) + kt*16);
        acc[ot] = mfmaf16(xf, wf, acc[ot]);   // D[n][o]
      }
    }
    const float* bias = p ? pb : tb;
    const float bscale = p ? 1.0f : LOG2E;
    unsigned short* outb =
        ws16 + (p ? VT : KT) + (((size_t)(b*4096 + n0 + w*32)) << 7);
    #pragma unroll
    for (int ot = 0; ot < 4; ++ot) {
      float bv = bias[ot*32 + l31] * bscale;
      #pragma unroll
      for (int r = 0; r < 16; ++r) {
        int row = (r & 3) + 8*(r >> 2) + 4*g;
        outb[(((size_t)row) << 7) + ot*32 + l31] = f2h(acc[ot][r] + bv);
      }
    }
  } else {
    #pragma unroll
    for (int kt = 0; kt < 16; ++kt) {
      half8 xf = *(const half8*)(xrow + kt*16);
      #pragma unroll
      for (int ot = 0; ot < 4; ++ot) {
        half8 wf = *(const half8*)(wbase + (((size_t)(ot*32 + l31)) << 8) + kt*16);
        acc[ot] = mfmaf16(wf, xf, acc[ot]);   // D[o][n]
      }
    }
    unsigned short* outb = ws16 + QT + (((size_t)(b*128)) << 12) + n0 + w*32 + l31;
    #pragma unroll
    for (int ot = 0; ot < 4; ++ot) {
      #pragma unroll
      for (int r = 0; r < 16; ++r) {
        int row = (r & 3) + 8*(r >> 2) + 4*g;
        int o = ot*32 + row;
        outb[((size_t)o) << 12] = f2h(acc[ot][r] + gb[o]);
      }
    }
  }
}

// ---------------------------------------------------------------------------
// Kernel 2: flash attention — cross-iteration software pipeline (T15).
// Iter t: stage V(t+2),Q(t+1) -> QK^T(t+1) -> softmax(t) -> PV(t).
// Independent V/Q double-buffers; one barrier/iter. LDS 64 KB:
//   Vbuf[0]@0, Vbuf[1]@16K, Qbuf[0]@32K, Qbuf[1]@48K.
// ---------------------------------------------------------------------------
__device__ __forceinline__ void stage_V(const unsigned short* __restrict__ ws16,
                                        int b, int m0_, int tid, int w,
                                        unsigned char* vdst) {
  const unsigned short* Vt = ws16 + VT;
  #pragma unroll
  for (int k = 0; k < 4; ++k) {
    int e = tid + (k << 8); int m = e >> 4, oc = e & 15;
    const unsigned short* src =
        Vt + (((size_t)(b*4096 + m0_ + m)) << 7) + ((oc*8) ^ ((m & 15)*8));
    gload16(src, vdst + ((k << 8) + (w << 6))*16);
  }
}
__device__ __forceinline__ void stage_Q(const unsigned short* __restrict__ ws16,
                                        int b, int m0_, int tid, int w,
                                        unsigned char* qdst) {
  const unsigned short* Qh = ws16 + QT;
  #pragma unroll
  for (int k = 0; k < 4; ++k) {
    int e = tid + (k << 8); int o = e >> 3, mc = e & 7;
    const unsigned short* src =
        Qh + (((size_t)(b*128 + o)) << 12) + m0_ + ((mc*8) ^ ((o & 7)*8));
    gload16(src, qdst + ((k << 8) + (w << 6))*16);
  }
}

__device__ __forceinline__ void qkt(const unsigned char* vbuf, const half8* kh,
                                    int l31, int g, f32x16& c0, f32x16& c1) {
  c0 = zero16(); c1 = zero16();
  __builtin_amdgcn_s_setprio(1);
  #pragma unroll
  for (int kt = 0; kt < 8; ++kt) {
    const int ob = (kt*32 + g*16) ^ ((l31 & 15)*16);
    half8 v0 = *(const half8*)(vbuf + l31*256 + ob);
    half8 v1 = *(const half8*)(vbuf + (32 + l31)*256 + ob);
    c0 = mfmaf16(v0, kh[kt], c0);
    c1 = mfmaf16(v1, kh[kt], c1);
  }
  __builtin_amdgcn_s_setprio(0);
}

__device__ __forceinline__ void smax_pv(f32x16& c0, f32x16& c1, f32x16* acc,
                                        float& mreg, float& lreg,
                                        const unsigned char* qbuf, int l31, int g) {
  // tree max over this lane's 32 values + cross-half swap
  float mx[8];
  #pragma unroll
  for (int i = 0; i < 8; ++i)
    mx[i] = fmaxf(fmaxf(c0[i], c0[i+8]), fmaxf(c1[i], c1[i+8]));
  #pragma unroll
  for (int i = 0; i < 4; ++i) mx[i] = fmaxf(mx[i], mx[i+4]);
  float tm = fmaxf(fmaxf(mx[0], mx[1]), fmaxf(mx[2], mx[3]));
  tm = fmaxf(tm, __shfl_xor(tm, 32));

  float f = 1.0f;
  if (__any(tm > mreg + 11.0f)) {       // T13 defer-max (log2 units)
    float mn = fmaxf(mreg, tm);
    f = ex2(mreg - mn);
    mreg = mn;
    #pragma unroll
    for (int r = 0; r < 16; ++r) {
      const int nl = (r & 3) + 8*(r >> 2) + 4*g;
      float fr = __shfl(f, nl);
      acc[0][r] *= fr; acc[1][r] *= fr; acc[2][r] *= fr; acc[3][r] *= fr;
    }
  }
  #pragma unroll
  for (int r = 0; r < 16; ++r) { c0[r] = ex2(c0[r] - mreg); }
  #pragma unroll
  for (int r = 0; r < 16; ++r) { c1[r] = ex2(c1[r] - mreg); }
  float sm[8];
  #pragma unroll
  for (int i = 0; i < 8; ++i) sm[i] = (c0[i] + c0[i+8]) + (c1[i] + c1[i+8]);
  #pragma unroll
  for (int i = 0; i < 4; ++i) sm[i] += sm[i+4];
  float ts = (sm[0] + sm[1]) + (sm[2] + sm[3]);
  ts += __shfl_xor(ts, 32);
  lreg = lreg * f + ts;

  // P -> A-fragments (in-register), then PV
  half8 pfr[4];
  pfr[0] = pfrag2(c0[0],c0[1],c0[2],c0[3],c0[4],c0[5],c0[6],c0[7]);
  pfr[1] = pfrag2(c0[8],c0[9],c0[10],c0[11],c0[12],c0[13],c0[14],c0[15]);
  pfr[2] = pfrag2(c1[0],c1[1],c1[2],c1[3],c1[4],c1[5],c1[6],c1[7]);
  pfr[3] = pfrag2(c1[8],c1[9],c1[10],c1[11],c1[12],c1[13],c1[14],c1[15]);

  __builtin_amdgcn_s_setprio(1);
  #pragma unroll
  for (int kt2 = 0; kt2 < 4; ++kt2) {
    const int qo = kt2*32 + g*16;
    #pragma unroll
    for (int ot = 0; ot < 4; ++ot) {
      const int o_ = ot*32 + l31;
      half8 qf = *(const half8*)(qbuf + o_*128 + (qo ^ ((o_ & 7)*16)));
      acc[ot] = mfmaf16(pfr[kt2], qf, acc[ot]);
    }
  }
  __builtin_amdgcn_s_setprio(0);
}

__global__ __launch_bounds__(256, 2)
void attn_kernel(unsigned short* __restrict__ ws16,
                 float* __restrict__ Mst, float* __restrict__ Lst) {
  const int L  = blockIdx.x;            // 512
  const int b  = L & 3;
  const int mh = (L >> 2) & 3;
  const int rb = L >> 4;
  const int r0 = rb * 128;
  const int mbase = mh * 1024;
  constexpr int NT = 16;

  const int tid  = threadIdx.x;
  const int w    = tid >> 6;
  const int lane = tid & 63;
  const int l31  = lane & 31;
  const int g    = lane >> 5;

  __shared__ __align__(16) unsigned char smem[65536];
  unsigned char* V0 = smem;
  unsigned char* V1 = smem + 16384;
  unsigned char* Q0 = smem + 32768;
  unsigned char* Q1 = smem + 49152;

  const int nrow = r0 + w*32 + l31;
  half8 kh[8];
  {
    const unsigned short* Kt = ws16 + KT + (((size_t)(b*4096 + nrow)) << 7);
    #pragma unroll
    for (int kt = 0; kt < 8; ++kt)
      kh[kt] = *(const half8*)(Kt + kt*16 + g*8);
  }

  f32x16 acc[4];
  #pragma unroll
  for (int ot = 0; ot < 4; ++ot) acc[ot] = zero16();
  float mreg = -INFINITY, lreg = 0.0f;

  f32x16 cA0, cA1, cB0, cB1;

  // prologue: V(0)->V1; then while QK^T(0) runs, stage V(1)->V0, Q(0)->Q0.
  stage_V(ws16, b, mbase, tid, w, V1);
  __syncthreads();
  stage_V(ws16, b, mbase + 64, tid, w, V0);
  stage_Q(ws16, b, mbase, tid, w, Q0);
  qkt(V1, kh, l31, g, cA0, cA1);        // S(0)
  __syncthreads();

  #pragma unroll 1
  for (int t = 0; t < NT; t += 2) {
    // even iter (q=0): CUR=A, NXT=B; reads V0/Q0, stages V1/Q1
    {
      if (t + 2 < NT) stage_V(ws16, b, mbase + (t+2)*64, tid, w, V1);
      stage_Q(ws16, b, mbase + (t+1)*64, tid, w, Q1);      // t+1 <= 15 always
      qkt(V0, kh, l31, g, cB0, cB1);                        // S(t+1)
      smax_pv(cA0, cA1, acc, mreg, lreg, Q0, l31, g);       // finish t
      __syncthreads();
    }
    // odd iter (q=1): CUR=B, NXT=A; reads V1/Q1, stages V0/Q0
    {
      const int t1 = t + 1;
      if (t1 + 2 < NT) stage_V(ws16, b, mbase + (t1+2)*64, tid, w, V0);
      if (t1 + 1 < NT) {
        stage_Q(ws16, b, mbase + (t1+1)*64, tid, w, Q0);
        qkt(V1, kh, l31, g, cA0, cA1);                      // S(t1+1)
      }
      smax_pv(cB0, cB1, acc, mreg, lreg, Q1, l31, g);       // finish t1
      __syncthreads();
    }
  }

  // epilogue: normalized fp16 partial -> OB[mh][b][n][o]
  unsigned short* Ob = ws16 + OB + (size_t)mh*OSZ + (((size_t)(b*4096)) << 7);
  const float linv_own = 1.0f / lreg;
  #pragma unroll
  for (int r = 0; r < 16; ++r) {
    const int nl = (r & 3) + 8*(r >> 2) + 4*g;
    const float linv = __shfl(linv_own, nl);
    const size_t nb = ((size_t)(r0 + w*32 + nl)) << 7;
    #pragma unroll
    for (int ot = 0; ot < 4; ++ot) {
      const int o_ = ot*32 + l31;
      Ob[nb + o_] = f2h(acc[ot][r] * linv);
    }
  }
  if (lane < 32) {
    const int n_ = r0 + w*32 + l31;
    Mst[((mh*4 + b) << 12) + n_] = mreg;   // log2 domain
    Lst[((mh*4 + b) << 12) + n_] = lreg;
  }
}

// ---------------------------------------------------------------------------
// Kernel 3: out projection via MFMA with fused 4-partial merge (unchanged).
// ---------------------------------------------------------------------------
__global__ __launch_bounds__(256)
void out_kernel(const float* __restrict__ x, const float* __restrict__ wb,
                const unsigned short* __restrict__ ws16,
                const float* __restrict__ Mst, const float* __restrict__ Lst,
                float* __restrict__ out) {
  const int L = blockIdx.x;            // 256
  const int b = L & 3, nt = L >> 2;
  const int n0 = nt * 64;
  const int tid = threadIdx.x, w = tid >> 6, lane = tid & 63;
  const int l31 = lane & 31, g = lane >> 5;
  const int nsub = w & 1, chalf = w >> 1;

  __shared__ float cs[4][64];
  if (tid < 64) {
    const int n_ = n0 + tid;
    float m0 = Mst[((0*4+b) << 12) + n_], l0 = Lst[((0*4+b) << 12) + n_];
    float m1 = Mst[((1*4+b) << 12) + n_], l1 = Lst[((1*4+b) << 12) + n_];
    float m2 = Mst[((2*4+b) << 12) + n_], l2 = Lst[((2*4+b) << 12) + n_];
    float m3 = Mst[((3*4+b) << 12) + n_], l3 = Lst[((3*4+b) << 12) + n_];
    float M = fmaxf(fmaxf(m0, m1), fmaxf(m2, m3));
    float w0 = l0 * exp2f(m0 - M);       // stats are log2-domain
    float w1 = l1 * exp2f(m1 - M);
    float w2 = l2 * exp2f(m2 - M);
    float w3 = l3 * exp2f(m3 - M);
    float inv = 1.0f / (w0 + w1 + w2 + w3);
    cs[0][tid] = w0*inv; cs[1][tid] = w1*inv; cs[2][tid] = w2*inv; cs[3][tid] = w3*inv;
  }
  __syncthreads();

  const int n_lane = n0 + nsub*32 + l31;
  unsigned csh[4];
  #pragma unroll
  for (int p = 0; p < 4; ++p) {
    float c = cs[p][nsub*32 + l31];
    csh[p] = pkf(c, c);
  }

  f32x16 acc[4];
  #pragma unroll
  for (int ct = 0; ct < 4; ++ct) acc[ct] = zero16();

  const unsigned short* ob = ws16 + OB + (((size_t)(b*4096 + n_lane)) << 7) + g*8;
  const unsigned short* wrow = ws16 + WOH + g*8;

  #pragma unroll
  for (int kt = 0; kt < 8; ++kt) {
    uN4 u0 = *(const uN4*)(ob + kt*16);
    uN4 u1 = *(const uN4*)(ob + OSZ + kt*16);
    uN4 u2 = *(const uN4*)(ob + 2*OSZ + kt*16);
    uN4 u3 = *(const uN4*)(ob + 3*OSZ + kt*16);
    union { uN4 u; half8 h; } m;
    #pragma unroll
    for (int i = 0; i < 4; ++i)
      m.u[i] = pkfma(u0[i], csh[0],
               pkfma(u1[i], csh[1],
               pkfma(u2[i], csh[2], pkmul(u3[i], csh[3]))));
    #pragma unroll
    for (int ct = 0; ct < 4; ++ct) {
      half8 wf = *(const half8*)(wrow + (((size_t)((chalf*4 + ct)*32 + l31)) << 7) + kt*16);
      acc[ct] = mfmaf16(wf, m.h, acc[ct]);   // D[c][n]
    }
  }

  #pragma unroll
  for (int ct = 0; ct < 4; ++ct) {
    #pragma unroll
    for (int r = 0; r < 16; ++r) {
      const int c = (chalf*4 + ct)*32 + (r & 3) + 8*(r >> 2) + 4*g;
      const size_t off = ((size_t)(b*256 + c) << 12) + n_lane;
      out[off] = acc[ct][r] + wb[c] + x[off];
    }
  }
}

extern "C" void kernel_launch(void* const* d_in, const int* in_sizes, int n_in,
                              void* d_out, int out_size, void* d_ws, size_t ws_size,
                              hipStream_t stream) {
  const float* x  = (const float*)d_in[0];
  const float* tw = (const float*)d_in[1];
  const float* tb = (const float*)d_in[2];
  const float* pw = (const float*)d_in[3];
  const float* pb = (const float*)d_in[4];
  const float* gw = (const float*)d_in[5];
  const float* gb = (const float*)d_in[6];
  const float* ww = (const float*)d_in[7];
  const float* wbb= (const float*)d_in[8];

  unsigned short* ws16 = (unsigned short*)d_ws;
  float* Mst = (float*)((char*)d_ws + STAT_BYTE);
  float* Lst = Mst + 16*4096;
  float* out = (float*)d_out;

  if (ws_size < 33554432u) return;

  prep_kernel<<<1024, 256, 0, stream>>>(x, tw, pw, gw, ww, ws16);
  proj_kernel<<<384, 256, 0, stream>>>(tb, pb, gb, ws16);
  attn_kernel<<<512, 256, 0, stream>>>(ws16, Mst, Lst);
  out_kernel<<<256, 256, 0, stream>>>(x, wbb, ws16, Mst, Lst, out);
}